// Round 7
// baseline (438.373 us; speedup 1.0000x reference)
//
#include <hip/hip_runtime.h>
#include <hip/hip_fp16.h>
#include <math.h>

#define KF 8
#define LL 8
#define TT (1 << 18)
#define FF 2
#define HID 64
#define INF 16          // L*F = MLP input dim
// Legacy strides for the unbucketed fallback kernels:
#define W1S 1056
#define BS  68

#define NENT (KF * LL * TT)           // 16,777,216 table entries
#define TAB_BYTES ((size_t)NENT * 4)  // half2 table: 64 MiB

// ---------------------------------------------------------------------------
// Round-7: accounting from r5/r6 — total 415us = ~150us harness restore
// (fixed) + ~50us repack (streaming floor) + 210us main. Main is pinned at
// 580MB L2-fill (FETCH) @ ~2.9 TB/s because EVERY XCD runs points of ALL 8
// clusters: each 4MB L2 faces the full 64MB random table -> 8x re-fetch
// from L3. Fix: bucket points by cluster, dispatch so cluster k runs only on
// blockIdx%8==k (HW round-robins consecutive blockIdx across the 8 XCDs) ->
// XCD k's L2 sees only cluster k's ~8MB slice. Side wins: per-block weights
// are single-cluster (LDS 38.4KB->4.5KB, bank conflicts -> 0, broadcasts).
// Per-point math identical to r5/r6 (absmax unchanged).
// Workspace: [half2 table 64Mi][cursors 8xu32 pad 256B][indices 8 x npts u32].
// ---------------------------------------------------------------------------

__global__ __launch_bounds__(256) void repack_tables_fp16(
    const float4* __restrict__ src, uint4* __restrict__ dst, int nthreads)
{
    const int gid = blockIdx.x * blockDim.x + threadIdx.x;
    if (gid >= nthreads) return;
    const size_t b = (size_t)gid * 4;            // float4 index (2 entries each)

    const float4 f0 = src[b + 0];
    const float4 f1 = src[b + 1];
    const float4 f2 = src[b + 2];
    const float4 f3 = src[b + 3];

    uint4 d0, d1;
    {
        __half2 h;
        h = __floats2half2_rn(f0.x, f0.y); d0.x = *reinterpret_cast<unsigned*>(&h);
        h = __floats2half2_rn(f0.z, f0.w); d0.y = *reinterpret_cast<unsigned*>(&h);
        h = __floats2half2_rn(f1.x, f1.y); d0.z = *reinterpret_cast<unsigned*>(&h);
        h = __floats2half2_rn(f1.z, f1.w); d0.w = *reinterpret_cast<unsigned*>(&h);
        h = __floats2half2_rn(f2.x, f2.y); d1.x = *reinterpret_cast<unsigned*>(&h);
        h = __floats2half2_rn(f2.z, f2.w); d1.y = *reinterpret_cast<unsigned*>(&h);
        h = __floats2half2_rn(f3.x, f3.y); d1.z = *reinterpret_cast<unsigned*>(&h);
        h = __floats2half2_rn(f3.z, f3.w); d1.w = *reinterpret_cast<unsigned*>(&h);
    }
    dst[(size_t)gid * 2 + 0] = d0;
    dst[(size_t)gid * 2 + 1] = d1;
}

__global__ void zero_cursors(unsigned* __restrict__ cursors)
{
    if (threadIdx.x < KF) cursors[threadIdx.x] = 0u;
}

// Phase 1: per-point argmin assignment + bucket scatter.
// LDS-aggregated ranks, one global atomicAdd per (block, cluster).
__global__ __launch_bounds__(256) void bucket_points(
    const float* __restrict__ positions,
    const float* __restrict__ centroids,
    unsigned* __restrict__ cursors,      // [KF] running cursors (pre-zeroed)
    unsigned* __restrict__ indices,      // [KF * npts] bucket storage
    int npts)
{
    __shared__ float sC[KF * 3];
    __shared__ unsigned lcnt[KF];
    __shared__ unsigned lbase[KF];

    const int tid = threadIdx.x;
    if (tid < KF * 3) sC[tid] = centroids[tid];
    if (tid < KF) lcnt[tid] = 0u;
    __syncthreads();

    const int gid = blockIdx.x * blockDim.x + tid;
    int assign = 0;
    unsigned lrank = 0;
    const bool valid = (gid < npts);
    if (valid) {
        const float px = positions[gid * 3 + 0];
        const float py = positions[gid * 3 + 1];
        const float pz = positions[gid * 3 + 2];
        float best = 1e30f;
        #pragma unroll
        for (int k = 0; k < KF; ++k) {
            float dx = px - sC[k * 3 + 0];
            float dy = py - sC[k * 3 + 1];
            float dz = pz - sC[k * 3 + 2];
            float d2 = fmaf(dx, dx, fmaf(dy, dy, dz * dz));
            bool lt = d2 < best;
            assign = lt ? k : assign;
            best = lt ? d2 : best;
        }
        lrank = atomicAdd(&lcnt[assign], 1u);
    }
    __syncthreads();
    if (tid < KF) lbase[tid] = atomicAdd(&cursors[tid], lcnt[tid]);
    __syncthreads();
    if (valid)
        indices[(size_t)assign * npts + lbase[assign] + lrank] = (unsigned)gid;
}

// Phase 2: density, one cluster per block, cluster = blockIdx & 7 (XCD pin).
__global__ __launch_bounds__(256) void propnet_density_bucketed(
    const float* __restrict__ positions,
    const __half2* __restrict__ tables,       // repacked half2 table (ws)
    const float* __restrict__ W1,
    const float* __restrict__ b1,
    const float* __restrict__ W2,
    const float* __restrict__ b2,
    const unsigned* __restrict__ cursors,     // final per-cluster counts
    const unsigned* __restrict__ indices,     // [KF * npts]
    float* __restrict__ out,
    int npts)
{
    const int k = blockIdx.x & 7;             // cluster == XCD (round-robin)
    const int s = blockIdx.x >> 3;            // slot within cluster
    const unsigned nk = cursors[k];
    if ((unsigned)(s * 256) >= nk) return;    // whole block idle

    __shared__ float sW1[INF * HID];          // 4096 B, single cluster
    __shared__ float sB1[HID];
    __shared__ float sW2[HID];

    const int tid = threadIdx.x;
    for (int idx = tid; idx < INF * HID; idx += blockDim.x)
        sW1[idx] = W1[k * (INF * HID) + idx];
    if (tid < HID) {
        sB1[tid] = b1[k * HID + tid];
        sW2[tid] = W2[k * HID + tid];
    }
    __syncthreads();

    const unsigned pos_in_bucket = (unsigned)(s * 256 + tid);
    if (pos_in_bucket >= nk) return;
    const unsigned pidx = indices[(size_t)k * npts + pos_in_bucket];

    const float px = positions[pidx * 3 + 0];
    const float py = positions[pidx * 3 + 1];
    const float pz = positions[pidx * 3 + 2];

    // ---- multiresolution hash encoding (half2 gathers, uniform table base) ----
    float enc[INF];
    const __half2* __restrict__ tab = tables + (size_t)k * (LL * (size_t)TT);

    #pragma unroll
    for (int l = 0; l < LL; ++l) {
        const float res = (float)(16 << l);
        const float sx = px * res, sy = py * res, sz = pz * res;
        const float fx = floorf(sx), fy = floorf(sy), fz = floorf(sz);
        const float wx = sx - fx, wy = sy - fy, wz = sz - fz;
        const unsigned ix = (unsigned)(int)fx;
        const unsigned iy = (unsigned)(int)fy;
        const unsigned iz = (unsigned)(int)fz;

        const __half2* __restrict__ tl = tab + (size_t)l * TT;

        const unsigned hx0 = ix;                         // prime 1
        const unsigned hx1 = ix + 1u;
        const unsigned hy0 = iy * 2654435761u;
        const unsigned hy1 = (iy + 1u) * 2654435761u;
        const unsigned hz0 = iz * 805459861u;
        const unsigned hz1 = (iz + 1u) * 805459861u;
        const unsigned M = TT - 1;

        // 8 independent 4B gathers — keep them all in flight
        const __half2 c000 = tl[(hx0 ^ hy0 ^ hz0) & M];
        const __half2 c001 = tl[(hx0 ^ hy0 ^ hz1) & M];
        const __half2 c010 = tl[(hx0 ^ hy1 ^ hz0) & M];
        const __half2 c011 = tl[(hx0 ^ hy1 ^ hz1) & M];
        const __half2 c100 = tl[(hx1 ^ hy0 ^ hz0) & M];
        const __half2 c101 = tl[(hx1 ^ hy0 ^ hz1) & M];
        const __half2 c110 = tl[(hx1 ^ hy1 ^ hz0) & M];
        const __half2 c111 = tl[(hx1 ^ hy1 ^ hz1) & M];

        const float ux = 1.f - wx, uy = 1.f - wy, uz = 1.f - wz;
        const float w000 = ux * uy * uz, w001 = ux * uy * wz;
        const float w010 = ux * wy * uz, w011 = ux * wy * wz;
        const float w100 = wx * uy * uz, w101 = wx * uy * wz;
        const float w110 = wx * wy * uz, w111 = wx * wy * wz;

        enc[l * 2 + 0] = __low2float(c000) * w000 + __low2float(c001) * w001
                       + __low2float(c010) * w010 + __low2float(c011) * w011
                       + __low2float(c100) * w100 + __low2float(c101) * w101
                       + __low2float(c110) * w110 + __low2float(c111) * w111;
        enc[l * 2 + 1] = __high2float(c000) * w000 + __high2float(c001) * w001
                       + __high2float(c010) * w010 + __high2float(c011) * w011
                       + __high2float(c100) * w100 + __high2float(c101) * w101
                       + __high2float(c110) * w110 + __high2float(c111) * w111;
    }

    // ---- MLP (single-cluster weights, wave-uniform LDS broadcasts) ----
    const float4* __restrict__ w1k = (const float4*)sW1;
    const float4* __restrict__ b1k = (const float4*)sB1;
    const float4* __restrict__ w2k = (const float4*)sW2;

    float outv = b2[k];
    #pragma unroll
    for (int j4 = 0; j4 < HID / 4; ++j4) {
        float4 a = b1k[j4];
        #pragma unroll
        for (int i = 0; i < INF; ++i) {
            const float4 w = w1k[i * (HID / 4) + j4];
            const float e = enc[i];
            a.x = fmaf(e, w.x, a.x);
            a.y = fmaf(e, w.y, a.y);
            a.z = fmaf(e, w.z, a.z);
            a.w = fmaf(e, w.w, a.w);
        }
        a.x = fmaxf(a.x, 0.f); a.y = fmaxf(a.y, 0.f);
        a.z = fmaxf(a.z, 0.f); a.w = fmaxf(a.w, 0.f);
        const float4 w2v = w2k[j4];
        outv = fmaf(a.x, w2v.x, outv);
        outv = fmaf(a.y, w2v.y, outv);
        outv = fmaf(a.z, w2v.z, outv);
        outv = fmaf(a.w, w2v.w, outv);
    }

    out[pidx] = expf(outv);
}

// ---------------- Fallback tier 1: unbucketed fp16 (round-5/6 kernel) -------
__global__ __launch_bounds__(256) void propnet_density_kernel_h(
    const float* __restrict__ positions,
    const float* __restrict__ centroids,
    const __half2* __restrict__ tables,
    const float* __restrict__ W1,
    const float* __restrict__ b1,
    const float* __restrict__ W2,
    const float* __restrict__ b2,
    float* __restrict__ out,
    int npts)
{
    __shared__ float sW1[KF * W1S];
    __shared__ float sB1[KF * BS];
    __shared__ float sW2[KF * BS];
    __shared__ float sB2[KF];
    __shared__ float sC[KF * 3];

    const int tid = threadIdx.x;

    for (int idx = tid; idx < KF * INF * HID; idx += blockDim.x) {
        int k = idx >> 10;
        int r = idx & 1023;
        sW1[k * W1S + r] = W1[idx];
    }
    for (int idx = tid; idx < KF * HID; idx += blockDim.x) {
        int k = idx >> 6;
        int r = idx & 63;
        sB1[k * BS + r] = b1[idx];
        sW2[k * BS + r] = W2[idx];
    }
    if (tid < KF) sB2[tid] = b2[tid];
    if (tid < KF * 3) sC[tid] = centroids[tid];
    __syncthreads();

    const int gid = blockIdx.x * blockDim.x + tid;
    if (gid >= npts) return;

    const float px = positions[gid * 3 + 0];
    const float py = positions[gid * 3 + 1];
    const float pz = positions[gid * 3 + 2];

    int assign = 0;
    float best = 1e30f;
    #pragma unroll
    for (int k = 0; k < KF; ++k) {
        float dx = px - sC[k * 3 + 0];
        float dy = py - sC[k * 3 + 1];
        float dz = pz - sC[k * 3 + 2];
        float d2 = fmaf(dx, dx, fmaf(dy, dy, dz * dz));
        bool lt = d2 < best;
        assign = lt ? k : assign;
        best = lt ? d2 : best;
    }

    float enc[INF];
    const __half2* __restrict__ tab =
        tables + (size_t)assign * (LL * (size_t)TT);

    #pragma unroll
    for (int l = 0; l < LL; ++l) {
        const float res = (float)(16 << l);
        const float sx = px * res, sy = py * res, sz = pz * res;
        const float fx = floorf(sx), fy = floorf(sy), fz = floorf(sz);
        const float wx = sx - fx, wy = sy - fy, wz = sz - fz;
        const unsigned ix = (unsigned)(int)fx;
        const unsigned iy = (unsigned)(int)fy;
        const unsigned iz = (unsigned)(int)fz;

        const __half2* __restrict__ tl = tab + (size_t)l * TT;

        const unsigned hx0 = ix;
        const unsigned hx1 = ix + 1u;
        const unsigned hy0 = iy * 2654435761u;
        const unsigned hy1 = (iy + 1u) * 2654435761u;
        const unsigned hz0 = iz * 805459861u;
        const unsigned hz1 = (iz + 1u) * 805459861u;
        const unsigned M = TT - 1;

        const __half2 c000 = tl[(hx0 ^ hy0 ^ hz0) & M];
        const __half2 c001 = tl[(hx0 ^ hy0 ^ hz1) & M];
        const __half2 c010 = tl[(hx0 ^ hy1 ^ hz0) & M];
        const __half2 c011 = tl[(hx0 ^ hy1 ^ hz1) & M];
        const __half2 c100 = tl[(hx1 ^ hy0 ^ hz0) & M];
        const __half2 c101 = tl[(hx1 ^ hy0 ^ hz1) & M];
        const __half2 c110 = tl[(hx1 ^ hy1 ^ hz0) & M];
        const __half2 c111 = tl[(hx1 ^ hy1 ^ hz1) & M];

        const float ux = 1.f - wx, uy = 1.f - wy, uz = 1.f - wz;
        const float w000 = ux * uy * uz, w001 = ux * uy * wz;
        const float w010 = ux * wy * uz, w011 = ux * wy * wz;
        const float w100 = wx * uy * uz, w101 = wx * uy * wz;
        const float w110 = wx * wy * uz, w111 = wx * wy * wz;

        enc[l * 2 + 0] = __low2float(c000) * w000 + __low2float(c001) * w001
                       + __low2float(c010) * w010 + __low2float(c011) * w011
                       + __low2float(c100) * w100 + __low2float(c101) * w101
                       + __low2float(c110) * w110 + __low2float(c111) * w111;
        enc[l * 2 + 1] = __high2float(c000) * w000 + __high2float(c001) * w001
                       + __high2float(c010) * w010 + __high2float(c011) * w011
                       + __high2float(c100) * w100 + __high2float(c101) * w101
                       + __high2float(c110) * w110 + __high2float(c111) * w111;
    }

    const float4* __restrict__ w1k = (const float4*)(sW1 + assign * W1S);
    const float4* __restrict__ b1k = (const float4*)(sB1 + assign * BS);
    const float4* __restrict__ w2k = (const float4*)(sW2 + assign * BS);

    float outv = sB2[assign];
    #pragma unroll
    for (int j4 = 0; j4 < HID / 4; ++j4) {
        float4 a = b1k[j4];
        #pragma unroll
        for (int i = 0; i < INF; ++i) {
            const float4 w = w1k[i * (HID / 4) + j4];
            const float e = enc[i];
            a.x = fmaf(e, w.x, a.x);
            a.y = fmaf(e, w.y, a.y);
            a.z = fmaf(e, w.z, a.z);
            a.w = fmaf(e, w.w, a.w);
        }
        a.x = fmaxf(a.x, 0.f); a.y = fmaxf(a.y, 0.f);
        a.z = fmaxf(a.z, 0.f); a.w = fmaxf(a.w, 0.f);
        const float4 w2v = w2k[j4];
        outv = fmaf(a.x, w2v.x, outv);
        outv = fmaf(a.y, w2v.y, outv);
        outv = fmaf(a.z, w2v.z, outv);
        outv = fmaf(a.w, w2v.w, outv);
    }

    out[gid] = expf(outv);
}

// ---------------- Fallback tier 2: fp32 (round-0 kernel) --------------------
__global__ __launch_bounds__(256) void propnet_density_kernel_f(
    const float* __restrict__ positions,
    const float* __restrict__ centroids,
    const float* __restrict__ tables,
    const float* __restrict__ W1,
    const float* __restrict__ b1,
    const float* __restrict__ W2,
    const float* __restrict__ b2,
    float* __restrict__ out,
    int npts)
{
    __shared__ float sW1[KF * W1S];
    __shared__ float sB1[KF * BS];
    __shared__ float sW2[KF * BS];
    __shared__ float sB2[KF];
    __shared__ float sC[KF * 3];

    const int tid = threadIdx.x;

    for (int idx = tid; idx < KF * INF * HID; idx += blockDim.x) {
        int k = idx >> 10;
        int r = idx & 1023;
        sW1[k * W1S + r] = W1[idx];
    }
    for (int idx = tid; idx < KF * HID; idx += blockDim.x) {
        int k = idx >> 6;
        int r = idx & 63;
        sB1[k * BS + r] = b1[idx];
        sW2[k * BS + r] = W2[idx];
    }
    if (tid < KF) sB2[tid] = b2[tid];
    if (tid < KF * 3) sC[tid] = centroids[tid];
    __syncthreads();

    const int gid = blockIdx.x * blockDim.x + tid;
    if (gid >= npts) return;

    const float px = positions[gid * 3 + 0];
    const float py = positions[gid * 3 + 1];
    const float pz = positions[gid * 3 + 2];

    int assign = 0;
    float best = 1e30f;
    #pragma unroll
    for (int k = 0; k < KF; ++k) {
        float dx = px - sC[k * 3 + 0];
        float dy = py - sC[k * 3 + 1];
        float dz = pz - sC[k * 3 + 2];
        float d2 = fmaf(dx, dx, fmaf(dy, dy, dz * dz));
        bool lt = d2 < best;
        assign = lt ? k : assign;
        best = lt ? d2 : best;
    }

    float enc[INF];
    const float2* __restrict__ tab =
        (const float2*)tables + (size_t)assign * (LL * (size_t)TT);

    #pragma unroll
    for (int l = 0; l < LL; ++l) {
        const float res = (float)(16 << l);
        const float sx = px * res, sy = py * res, sz = pz * res;
        const float fx = floorf(sx), fy = floorf(sy), fz = floorf(sz);
        const float wx = sx - fx, wy = sy - fy, wz = sz - fz;
        const unsigned ix = (unsigned)(int)fx;
        const unsigned iy = (unsigned)(int)fy;
        const unsigned iz = (unsigned)(int)fz;

        const float2* __restrict__ tl = tab + (size_t)l * TT;

        const unsigned hx0 = ix;
        const unsigned hx1 = ix + 1u;
        const unsigned hy0 = iy * 2654435761u;
        const unsigned hy1 = (iy + 1u) * 2654435761u;
        const unsigned hz0 = iz * 805459861u;
        const unsigned hz1 = (iz + 1u) * 805459861u;
        const unsigned M = TT - 1;

        const float2 c000 = tl[(hx0 ^ hy0 ^ hz0) & M];
        const float2 c001 = tl[(hx0 ^ hy0 ^ hz1) & M];
        const float2 c010 = tl[(hx0 ^ hy1 ^ hz0) & M];
        const float2 c011 = tl[(hx0 ^ hy1 ^ hz1) & M];
        const float2 c100 = tl[(hx1 ^ hy0 ^ hz0) & M];
        const float2 c101 = tl[(hx1 ^ hy0 ^ hz1) & M];
        const float2 c110 = tl[(hx1 ^ hy1 ^ hz0) & M];
        const float2 c111 = tl[(hx1 ^ hy1 ^ hz1) & M];

        const float ux = 1.f - wx, uy = 1.f - wy, uz = 1.f - wz;
        const float w000 = ux * uy * uz, w001 = ux * uy * wz;
        const float w010 = ux * wy * uz, w011 = ux * wy * wz;
        const float w100 = wx * uy * uz, w101 = wx * uy * wz;
        const float w110 = wx * wy * uz, w111 = wx * wy * wz;

        enc[l * 2 + 0] = c000.x * w000 + c001.x * w001 + c010.x * w010 + c011.x * w011
                       + c100.x * w100 + c101.x * w101 + c110.x * w110 + c111.x * w111;
        enc[l * 2 + 1] = c000.y * w000 + c001.y * w001 + c010.y * w010 + c011.y * w011
                       + c100.y * w100 + c101.y * w101 + c110.y * w110 + c111.y * w111;
    }

    const float4* __restrict__ w1k = (const float4*)(sW1 + assign * W1S);
    const float4* __restrict__ b1k = (const float4*)(sB1 + assign * BS);
    const float4* __restrict__ w2k = (const float4*)(sW2 + assign * BS);

    float outv = sB2[assign];
    #pragma unroll
    for (int j4 = 0; j4 < HID / 4; ++j4) {
        float4 a = b1k[j4];
        #pragma unroll
        for (int i = 0; i < INF; ++i) {
            const float4 w = w1k[i * (HID / 4) + j4];
            const float e = enc[i];
            a.x = fmaf(e, w.x, a.x);
            a.y = fmaf(e, w.y, a.y);
            a.z = fmaf(e, w.z, a.z);
            a.w = fmaf(e, w.w, a.w);
        }
        a.x = fmaxf(a.x, 0.f); a.y = fmaxf(a.y, 0.f);
        a.z = fmaxf(a.z, 0.f); a.w = fmaxf(a.w, 0.f);
        const float4 w2v = w2k[j4];
        outv = fmaf(a.x, w2v.x, outv);
        outv = fmaf(a.y, w2v.y, outv);
        outv = fmaf(a.z, w2v.z, outv);
        outv = fmaf(a.w, w2v.w, outv);
    }

    out[gid] = expf(outv);
}

extern "C" void kernel_launch(void* const* d_in, const int* in_sizes, int n_in,
                              void* d_out, int out_size, void* d_ws, size_t ws_size,
                              hipStream_t stream) {
    const float* positions = (const float*)d_in[0];
    const float* centroids = (const float*)d_in[1];
    const float* tables    = (const float*)d_in[2];
    const float* W1        = (const float*)d_in[3];
    const float* b1        = (const float*)d_in[4];
    const float* W2        = (const float*)d_in[5];
    const float* b2        = (const float*)d_in[6];
    float* out = (float*)d_out;

    const int npts = in_sizes[0] / 3;
    const int block = 256;
    const int nb = (npts + block - 1) / block;        // point-blocks

    const size_t need_h    = TAB_BYTES;                                   // 64 Mi
    const size_t need_full = TAB_BYTES + 256 + (size_t)KF * npts * 4;     // ~80 Mi

    if (ws_size >= need_full && d_ws != nullptr) {
        char* base = (char*)d_ws;
        __half2*  wsTab   = (__half2*)base;
        unsigned* cursors = (unsigned*)(base + TAB_BYTES);
        unsigned* indices = (unsigned*)(base + TAB_BYTES + 256);

        const int rthreads = NENT / 8;
        repack_tables_fp16<<<rthreads / 256, 256, 0, stream>>>(
            (const float4*)tables, (uint4*)wsTab, rthreads);
        zero_cursors<<<1, 64, 0, stream>>>(cursors);
        bucket_points<<<nb, block, 0, stream>>>(
            positions, centroids, cursors, indices, npts);
        // 8 clusters x nb slots; cluster = blockIdx & 7 pins to one XCD.
        propnet_density_bucketed<<<8 * nb, block, 0, stream>>>(
            positions, wsTab, W1, b1, W2, b2, cursors, indices, out, npts);
    } else if (ws_size >= need_h && d_ws != nullptr) {
        const int rthreads = NENT / 8;
        repack_tables_fp16<<<rthreads / 256, 256, 0, stream>>>(
            (const float4*)tables, (uint4*)d_ws, rthreads);
        propnet_density_kernel_h<<<nb, block, 0, stream>>>(
            positions, centroids, (const __half2*)d_ws, W1, b1, W2, b2, out, npts);
    } else {
        propnet_density_kernel_f<<<nb, block, 0, stream>>>(
            positions, centroids, tables, W1, b1, W2, b2, out, npts);
    }
}

// Round 8
// 366.806 us; speedup vs baseline: 1.1951x; 1.1951x over previous
//
#include <hip/hip_runtime.h>
#include <hip/hip_fp16.h>
#include <math.h>

#define KF 8
#define LL 8
#define TT (1 << 18)
#define FF 2
#define HID 64
#define INF 16          // L*F = MLP input dim
// Legacy strides for the unbucketed fallback kernels:
#define W1S 1056
#define BS  68

#define NENT (KF * LL * TT)           // 16,777,216 table entries
#define TAB_BYTES ((size_t)NENT * 4)  // half2 table: 64 MiB

// ---------------------------------------------------------------------------
// Round-8: r7 proved the op is latency x concurrency bound (FETCH -3.2x,
// time flat) and that hard cluster->XCD pinning costs half the concurrency
// (occupancy 38->21%: XCD imbalance ~2x + 87% instant-exit blocks). Fix:
// BALANCED chunked-XCD dispatch. Pad each cluster bucket to 256-pt blocks,
// concatenate virtually; chunked swizzle v=(b&7)*cpx+(b>>3) gives XCD j the
// j-th contiguous 1/8 of virtual blocks -> exactly npts/8 points per XCD
// (perfect balance), while each XCD touches only the 1-2 clusters its chunk
// spans (~8-16MB table slice: locality mostly kept). Every block works; one
// cluster per block (4.6KB LDS, conflict-free broadcast weights).
// Model: keep r7's ~83ns L2-local latency, restore >=96 outstanding/CU
// -> main kernel ~90-140us.
// ---------------------------------------------------------------------------

__global__ __launch_bounds__(256) void repack_tables_fp16(
    const float4* __restrict__ src, uint4* __restrict__ dst, int nthreads)
{
    const int gid = blockIdx.x * blockDim.x + threadIdx.x;
    if (gid >= nthreads) return;
    const size_t b = (size_t)gid * 4;            // float4 index (2 entries each)

    const float4 f0 = src[b + 0];
    const float4 f1 = src[b + 1];
    const float4 f2 = src[b + 2];
    const float4 f3 = src[b + 3];

    uint4 d0, d1;
    {
        __half2 h;
        h = __floats2half2_rn(f0.x, f0.y); d0.x = *reinterpret_cast<unsigned*>(&h);
        h = __floats2half2_rn(f0.z, f0.w); d0.y = *reinterpret_cast<unsigned*>(&h);
        h = __floats2half2_rn(f1.x, f1.y); d0.z = *reinterpret_cast<unsigned*>(&h);
        h = __floats2half2_rn(f1.z, f1.w); d0.w = *reinterpret_cast<unsigned*>(&h);
        h = __floats2half2_rn(f2.x, f2.y); d1.x = *reinterpret_cast<unsigned*>(&h);
        h = __floats2half2_rn(f2.z, f2.w); d1.y = *reinterpret_cast<unsigned*>(&h);
        h = __floats2half2_rn(f3.x, f3.y); d1.z = *reinterpret_cast<unsigned*>(&h);
        h = __floats2half2_rn(f3.z, f3.w); d1.w = *reinterpret_cast<unsigned*>(&h);
    }
    dst[(size_t)gid * 2 + 0] = d0;
    dst[(size_t)gid * 2 + 1] = d1;
}

__global__ void zero_cursors(unsigned* __restrict__ cursors)
{
    if (threadIdx.x < KF) cursors[threadIdx.x] = 0u;
}

// Phase 1: per-point argmin assignment + bucket scatter.
// LDS-aggregated ranks, one global atomicAdd per (block, cluster).
__global__ __launch_bounds__(256) void bucket_points(
    const float* __restrict__ positions,
    const float* __restrict__ centroids,
    unsigned* __restrict__ cursors,      // [KF] running cursors (pre-zeroed)
    unsigned* __restrict__ indices,      // [KF * npts] bucket storage
    int npts)
{
    __shared__ float sC[KF * 3];
    __shared__ unsigned lcnt[KF];
    __shared__ unsigned lbase[KF];

    const int tid = threadIdx.x;
    if (tid < KF * 3) sC[tid] = centroids[tid];
    if (tid < KF) lcnt[tid] = 0u;
    __syncthreads();

    const int gid = blockIdx.x * blockDim.x + tid;
    int assign = 0;
    unsigned lrank = 0;
    const bool valid = (gid < npts);
    if (valid) {
        const float px = positions[gid * 3 + 0];
        const float py = positions[gid * 3 + 1];
        const float pz = positions[gid * 3 + 2];
        float best = 1e30f;
        #pragma unroll
        for (int k = 0; k < KF; ++k) {
            float dx = px - sC[k * 3 + 0];
            float dy = py - sC[k * 3 + 1];
            float dz = pz - sC[k * 3 + 2];
            float d2 = fmaf(dx, dx, fmaf(dy, dy, dz * dz));
            bool lt = d2 < best;
            assign = lt ? k : assign;
            best = lt ? d2 : best;
        }
        lrank = atomicAdd(&lcnt[assign], 1u);
    }
    __syncthreads();
    if (tid < KF) lbase[tid] = atomicAdd(&cursors[tid], lcnt[tid]);
    __syncthreads();
    if (valid)
        indices[(size_t)assign * npts + lbase[assign] + lrank] = (unsigned)gid;
}

// Phase 2: balanced chunked-XCD density kernel.
// Virtual block v=(b&7)*cpx+(b>>3): XCD j = b&7 gets contiguous v-chunk
// [j*cpx, (j+1)*cpx) of the padded-concatenated bucket space.
__global__ __launch_bounds__(256) void propnet_density_balanced(
    const float* __restrict__ positions,
    const __half2* __restrict__ tables,       // repacked half2 table (ws)
    const float* __restrict__ W1,
    const float* __restrict__ b1,
    const float* __restrict__ W2,
    const float* __restrict__ b2,
    const unsigned* __restrict__ cursors,     // final per-cluster counts
    const unsigned* __restrict__ indices,     // [KF * npts]
    float* __restrict__ out,
    int npts, int cpx)
{
    __shared__ float sW1[INF * HID];          // 4096 B, single cluster
    __shared__ float sB1[HID];
    __shared__ float sW2[HID];
    __shared__ unsigned snk[KF];

    const int tid = threadIdx.x;
    const int b = blockIdx.x;
    const int v = (b & 7) * cpx + (b >> 3);   // chunked XCD swizzle

    if (tid < KF) snk[tid] = cursors[tid];
    __syncthreads();

    // Locate (cluster k, slot) for virtual block v in the padded-block space.
    // All threads compute redundantly from LDS (8 iterations, registers).
    int k = -1;
    unsigned slot = 0, nk = 0, acc = 0;
    #pragma unroll
    for (int kk = 0; kk < KF; ++kk) {
        const unsigned n = snk[kk];
        const unsigned nbk = (n + 255u) >> 8;        // padded blocks for kk
        if (k < 0 && (unsigned)v < acc + nbk) {
            k = kk; slot = (unsigned)v - acc; nk = n;
        }
        acc += nbk;
    }
    if (k < 0) return;                               // v beyond vtotal (few)

    // Single-cluster weight staging (coalesced; wave-uniform reads later).
    for (int idx = tid; idx < INF * HID; idx += blockDim.x)
        sW1[idx] = W1[k * (INF * HID) + idx];
    if (tid < HID) {
        sB1[tid] = b1[k * HID + tid];
        sW2[tid] = W2[k * HID + tid];
    }
    __syncthreads();

    const unsigned rank = slot * 256u + (unsigned)tid;
    if (rank >= nk) return;                          // tail threads only
    const unsigned pidx = indices[(size_t)k * npts + rank];

    const float px = positions[pidx * 3 + 0];
    const float py = positions[pidx * 3 + 1];
    const float pz = positions[pidx * 3 + 2];

    // ---- multiresolution hash encoding (half2 gathers, uniform table base) ----
    float enc[INF];
    const __half2* __restrict__ tab = tables + (size_t)k * (LL * (size_t)TT);

    #pragma unroll
    for (int l = 0; l < LL; ++l) {
        const float res = (float)(16 << l);
        const float sx = px * res, sy = py * res, sz = pz * res;
        const float fx = floorf(sx), fy = floorf(sy), fz = floorf(sz);
        const float wx = sx - fx, wy = sy - fy, wz = sz - fz;
        const unsigned ix = (unsigned)(int)fx;
        const unsigned iy = (unsigned)(int)fy;
        const unsigned iz = (unsigned)(int)fz;

        const __half2* __restrict__ tl = tab + (size_t)l * TT;

        const unsigned hx0 = ix;                         // prime 1
        const unsigned hx1 = ix + 1u;
        const unsigned hy0 = iy * 2654435761u;
        const unsigned hy1 = (iy + 1u) * 2654435761u;
        const unsigned hz0 = iz * 805459861u;
        const unsigned hz1 = (iz + 1u) * 805459861u;
        const unsigned M = TT - 1;

        // 8 independent 4B gathers — keep them all in flight
        const __half2 c000 = tl[(hx0 ^ hy0 ^ hz0) & M];
        const __half2 c001 = tl[(hx0 ^ hy0 ^ hz1) & M];
        const __half2 c010 = tl[(hx0 ^ hy1 ^ hz0) & M];
        const __half2 c011 = tl[(hx0 ^ hy1 ^ hz1) & M];
        const __half2 c100 = tl[(hx1 ^ hy0 ^ hz0) & M];
        const __half2 c101 = tl[(hx1 ^ hy0 ^ hz1) & M];
        const __half2 c110 = tl[(hx1 ^ hy1 ^ hz0) & M];
        const __half2 c111 = tl[(hx1 ^ hy1 ^ hz1) & M];

        const float ux = 1.f - wx, uy = 1.f - wy, uz = 1.f - wz;
        const float w000 = ux * uy * uz, w001 = ux * uy * wz;
        const float w010 = ux * wy * uz, w011 = ux * wy * wz;
        const float w100 = wx * uy * uz, w101 = wx * uy * wz;
        const float w110 = wx * wy * uz, w111 = wx * wy * wz;

        enc[l * 2 + 0] = __low2float(c000) * w000 + __low2float(c001) * w001
                       + __low2float(c010) * w010 + __low2float(c011) * w011
                       + __low2float(c100) * w100 + __low2float(c101) * w101
                       + __low2float(c110) * w110 + __low2float(c111) * w111;
        enc[l * 2 + 1] = __high2float(c000) * w000 + __high2float(c001) * w001
                       + __high2float(c010) * w010 + __high2float(c011) * w011
                       + __high2float(c100) * w100 + __high2float(c101) * w101
                       + __high2float(c110) * w110 + __high2float(c111) * w111;
    }

    // ---- MLP (single-cluster weights, wave-uniform LDS broadcasts) ----
    const float4* __restrict__ w1k = (const float4*)sW1;
    const float4* __restrict__ b1k = (const float4*)sB1;
    const float4* __restrict__ w2k = (const float4*)sW2;

    float outv = b2[k];
    #pragma unroll
    for (int j4 = 0; j4 < HID / 4; ++j4) {
        float4 a = b1k[j4];
        #pragma unroll
        for (int i = 0; i < INF; ++i) {
            const float4 w = w1k[i * (HID / 4) + j4];
            const float e = enc[i];
            a.x = fmaf(e, w.x, a.x);
            a.y = fmaf(e, w.y, a.y);
            a.z = fmaf(e, w.z, a.z);
            a.w = fmaf(e, w.w, a.w);
        }
        a.x = fmaxf(a.x, 0.f); a.y = fmaxf(a.y, 0.f);
        a.z = fmaxf(a.z, 0.f); a.w = fmaxf(a.w, 0.f);
        const float4 w2v = w2k[j4];
        outv = fmaf(a.x, w2v.x, outv);
        outv = fmaf(a.y, w2v.y, outv);
        outv = fmaf(a.z, w2v.z, outv);
        outv = fmaf(a.w, w2v.w, outv);
    }

    out[pidx] = expf(outv);
}

// ---------------- Fallback tier 1: unbucketed fp16 (round-5/6 kernel) -------
__global__ __launch_bounds__(256) void propnet_density_kernel_h(
    const float* __restrict__ positions,
    const float* __restrict__ centroids,
    const __half2* __restrict__ tables,
    const float* __restrict__ W1,
    const float* __restrict__ b1,
    const float* __restrict__ W2,
    const float* __restrict__ b2,
    float* __restrict__ out,
    int npts)
{
    __shared__ float sW1[KF * W1S];
    __shared__ float sB1[KF * BS];
    __shared__ float sW2[KF * BS];
    __shared__ float sB2[KF];
    __shared__ float sC[KF * 3];

    const int tid = threadIdx.x;

    for (int idx = tid; idx < KF * INF * HID; idx += blockDim.x) {
        int k = idx >> 10;
        int r = idx & 1023;
        sW1[k * W1S + r] = W1[idx];
    }
    for (int idx = tid; idx < KF * HID; idx += blockDim.x) {
        int k = idx >> 6;
        int r = idx & 63;
        sB1[k * BS + r] = b1[idx];
        sW2[k * BS + r] = W2[idx];
    }
    if (tid < KF) sB2[tid] = b2[tid];
    if (tid < KF * 3) sC[tid] = centroids[tid];
    __syncthreads();

    const int gid = blockIdx.x * blockDim.x + tid;
    if (gid >= npts) return;

    const float px = positions[gid * 3 + 0];
    const float py = positions[gid * 3 + 1];
    const float pz = positions[gid * 3 + 2];

    int assign = 0;
    float best = 1e30f;
    #pragma unroll
    for (int k = 0; k < KF; ++k) {
        float dx = px - sC[k * 3 + 0];
        float dy = py - sC[k * 3 + 1];
        float dz = pz - sC[k * 3 + 2];
        float d2 = fmaf(dx, dx, fmaf(dy, dy, dz * dz));
        bool lt = d2 < best;
        assign = lt ? k : assign;
        best = lt ? d2 : best;
    }

    float enc[INF];
    const __half2* __restrict__ tab =
        tables + (size_t)assign * (LL * (size_t)TT);

    #pragma unroll
    for (int l = 0; l < LL; ++l) {
        const float res = (float)(16 << l);
        const float sx = px * res, sy = py * res, sz = pz * res;
        const float fx = floorf(sx), fy = floorf(sy), fz = floorf(sz);
        const float wx = sx - fx, wy = sy - fy, wz = sz - fz;
        const unsigned ix = (unsigned)(int)fx;
        const unsigned iy = (unsigned)(int)fy;
        const unsigned iz = (unsigned)(int)fz;

        const __half2* __restrict__ tl = tab + (size_t)l * TT;

        const unsigned hx0 = ix;
        const unsigned hx1 = ix + 1u;
        const unsigned hy0 = iy * 2654435761u;
        const unsigned hy1 = (iy + 1u) * 2654435761u;
        const unsigned hz0 = iz * 805459861u;
        const unsigned hz1 = (iz + 1u) * 805459861u;
        const unsigned M = TT - 1;

        const __half2 c000 = tl[(hx0 ^ hy0 ^ hz0) & M];
        const __half2 c001 = tl[(hx0 ^ hy0 ^ hz1) & M];
        const __half2 c010 = tl[(hx0 ^ hy1 ^ hz0) & M];
        const __half2 c011 = tl[(hx0 ^ hy1 ^ hz1) & M];
        const __half2 c100 = tl[(hx1 ^ hy0 ^ hz0) & M];
        const __half2 c101 = tl[(hx1 ^ hy0 ^ hz1) & M];
        const __half2 c110 = tl[(hx1 ^ hy1 ^ hz0) & M];
        const __half2 c111 = tl[(hx1 ^ hy1 ^ hz1) & M];

        const float ux = 1.f - wx, uy = 1.f - wy, uz = 1.f - wz;
        const float w000 = ux * uy * uz, w001 = ux * uy * wz;
        const float w010 = ux * wy * uz, w011 = ux * wy * wz;
        const float w100 = wx * uy * uz, w101 = wx * uy * wz;
        const float w110 = wx * wy * uz, w111 = wx * wy * wz;

        enc[l * 2 + 0] = __low2float(c000) * w000 + __low2float(c001) * w001
                       + __low2float(c010) * w010 + __low2float(c011) * w011
                       + __low2float(c100) * w100 + __low2float(c101) * w101
                       + __low2float(c110) * w110 + __low2float(c111) * w111;
        enc[l * 2 + 1] = __high2float(c000) * w000 + __high2float(c001) * w001
                       + __high2float(c010) * w010 + __high2float(c011) * w011
                       + __high2float(c100) * w100 + __high2float(c101) * w101
                       + __high2float(c110) * w110 + __high2float(c111) * w111;
    }

    const float4* __restrict__ w1k = (const float4*)(sW1 + assign * W1S);
    const float4* __restrict__ b1k = (const float4*)(sB1 + assign * BS);
    const float4* __restrict__ w2k = (const float4*)(sW2 + assign * BS);

    float outv = sB2[assign];
    #pragma unroll
    for (int j4 = 0; j4 < HID / 4; ++j4) {
        float4 a = b1k[j4];
        #pragma unroll
        for (int i = 0; i < INF; ++i) {
            const float4 w = w1k[i * (HID / 4) + j4];
            const float e = enc[i];
            a.x = fmaf(e, w.x, a.x);
            a.y = fmaf(e, w.y, a.y);
            a.z = fmaf(e, w.z, a.z);
            a.w = fmaf(e, w.w, a.w);
        }
        a.x = fmaxf(a.x, 0.f); a.y = fmaxf(a.y, 0.f);
        a.z = fmaxf(a.z, 0.f); a.w = fmaxf(a.w, 0.f);
        const float4 w2v = w2k[j4];
        outv = fmaf(a.x, w2v.x, outv);
        outv = fmaf(a.y, w2v.y, outv);
        outv = fmaf(a.z, w2v.z, outv);
        outv = fmaf(a.w, w2v.w, outv);
    }

    out[gid] = expf(outv);
}

// ---------------- Fallback tier 2: fp32 (round-0 kernel) --------------------
__global__ __launch_bounds__(256) void propnet_density_kernel_f(
    const float* __restrict__ positions,
    const float* __restrict__ centroids,
    const float* __restrict__ tables,
    const float* __restrict__ W1,
    const float* __restrict__ b1,
    const float* __restrict__ W2,
    const float* __restrict__ b2,
    float* __restrict__ out,
    int npts)
{
    __shared__ float sW1[KF * W1S];
    __shared__ float sB1[KF * BS];
    __shared__ float sW2[KF * BS];
    __shared__ float sB2[KF];
    __shared__ float sC[KF * 3];

    const int tid = threadIdx.x;

    for (int idx = tid; idx < KF * INF * HID; idx += blockDim.x) {
        int k = idx >> 10;
        int r = idx & 1023;
        sW1[k * W1S + r] = W1[idx];
    }
    for (int idx = tid; idx < KF * HID; idx += blockDim.x) {
        int k = idx >> 6;
        int r = idx & 63;
        sB1[k * BS + r] = b1[idx];
        sW2[k * BS + r] = W2[idx];
    }
    if (tid < KF) sB2[tid] = b2[tid];
    if (tid < KF * 3) sC[tid] = centroids[tid];
    __syncthreads();

    const int gid = blockIdx.x * blockDim.x + tid;
    if (gid >= npts) return;

    const float px = positions[gid * 3 + 0];
    const float py = positions[gid * 3 + 1];
    const float pz = positions[gid * 3 + 2];

    int assign = 0;
    float best = 1e30f;
    #pragma unroll
    for (int k = 0; k < KF; ++k) {
        float dx = px - sC[k * 3 + 0];
        float dy = py - sC[k * 3 + 1];
        float dz = pz - sC[k * 3 + 2];
        float d2 = fmaf(dx, dx, fmaf(dy, dy, dz * dz));
        bool lt = d2 < best;
        assign = lt ? k : assign;
        best = lt ? d2 : best;
    }

    float enc[INF];
    const float2* __restrict__ tab =
        (const float2*)tables + (size_t)assign * (LL * (size_t)TT);

    #pragma unroll
    for (int l = 0; l < LL; ++l) {
        const float res = (float)(16 << l);
        const float sx = px * res, sy = py * res, sz = pz * res;
        const float fx = floorf(sx), fy = floorf(sy), fz = floorf(sz);
        const float wx = sx - fx, wy = sy - fy, wz = sz - fz;
        const unsigned ix = (unsigned)(int)fx;
        const unsigned iy = (unsigned)(int)fy;
        const unsigned iz = (unsigned)(int)fz;

        const float2* __restrict__ tl = tab + (size_t)l * TT;

        const unsigned hx0 = ix;
        const unsigned hx1 = ix + 1u;
        const unsigned hy0 = iy * 2654435761u;
        const unsigned hy1 = (iy + 1u) * 2654435761u;
        const unsigned hz0 = iz * 805459861u;
        const unsigned hz1 = (iz + 1u) * 805459861u;
        const unsigned M = TT - 1;

        const float2 c000 = tl[(hx0 ^ hy0 ^ hz0) & M];
        const float2 c001 = tl[(hx0 ^ hy0 ^ hz1) & M];
        const float2 c010 = tl[(hx0 ^ hy1 ^ hz0) & M];
        const float2 c011 = tl[(hx0 ^ hy1 ^ hz1) & M];
        const float2 c100 = tl[(hx1 ^ hy0 ^ hz0) & M];
        const float2 c101 = tl[(hx1 ^ hy0 ^ hz1) & M];
        const float2 c110 = tl[(hx1 ^ hy1 ^ hz0) & M];
        const float2 c111 = tl[(hx1 ^ hy1 ^ hz1) & M];

        const float ux = 1.f - wx, uy = 1.f - wy, uz = 1.f - wz;
        const float w000 = ux * uy * uz, w001 = ux * uy * wz;
        const float w010 = ux * wy * uz, w011 = ux * wy * wz;
        const float w100 = wx * uy * uz, w101 = wx * uy * wz;
        const float w110 = wx * wy * uz, w111 = wx * wy * wz;

        enc[l * 2 + 0] = c000.x * w000 + c001.x * w001 + c010.x * w010 + c011.x * w011
                       + c100.x * w100 + c101.x * w101 + c110.x * w110 + c111.x * w111;
        enc[l * 2 + 1] = c000.y * w000 + c001.y * w001 + c010.y * w010 + c011.y * w011
                       + c100.y * w100 + c101.y * w101 + c110.y * w110 + c111.y * w111;
    }

    const float4* __restrict__ w1k = (const float4*)(sW1 + assign * W1S);
    const float4* __restrict__ b1k = (const float4*)(sB1 + assign * BS);
    const float4* __restrict__ w2k = (const float4*)(sW2 + assign * BS);

    float outv = sB2[assign];
    #pragma unroll
    for (int j4 = 0; j4 < HID / 4; ++j4) {
        float4 a = b1k[j4];
        #pragma unroll
        for (int i = 0; i < INF; ++i) {
            const float4 w = w1k[i * (HID / 4) + j4];
            const float e = enc[i];
            a.x = fmaf(e, w.x, a.x);
            a.y = fmaf(e, w.y, a.y);
            a.z = fmaf(e, w.z, a.z);
            a.w = fmaf(e, w.w, a.w);
        }
        a.x = fmaxf(a.x, 0.f); a.y = fmaxf(a.y, 0.f);
        a.z = fmaxf(a.z, 0.f); a.w = fmaxf(a.w, 0.f);
        const float4 w2v = w2k[j4];
        outv = fmaf(a.x, w2v.x, outv);
        outv = fmaf(a.y, w2v.y, outv);
        outv = fmaf(a.z, w2v.z, outv);
        outv = fmaf(a.w, w2v.w, outv);
    }

    out[gid] = expf(outv);
}

extern "C" void kernel_launch(void* const* d_in, const int* in_sizes, int n_in,
                              void* d_out, int out_size, void* d_ws, size_t ws_size,
                              hipStream_t stream) {
    const float* positions = (const float*)d_in[0];
    const float* centroids = (const float*)d_in[1];
    const float* tables    = (const float*)d_in[2];
    const float* W1        = (const float*)d_in[3];
    const float* b1        = (const float*)d_in[4];
    const float* W2        = (const float*)d_in[5];
    const float* b2        = (const float*)d_in[6];
    float* out = (float*)d_out;

    const int npts = in_sizes[0] / 3;
    const int block = 256;
    const int nb = (npts + block - 1) / block;        // point-blocks

    const size_t need_h    = TAB_BYTES;                                   // 64 Mi
    const size_t need_full = TAB_BYTES + 256 + (size_t)KF * npts * 4;     // ~80 Mi

    if (ws_size >= need_full && d_ws != nullptr) {
        char* base = (char*)d_ws;
        __half2*  wsTab   = (__half2*)base;
        unsigned* cursors = (unsigned*)(base + TAB_BYTES);
        unsigned* indices = (unsigned*)(base + TAB_BYTES + 256);

        const int rthreads = NENT / 8;
        repack_tables_fp16<<<rthreads / 256, 256, 0, stream>>>(
            (const float4*)tables, (uint4*)wsTab, rthreads);
        zero_cursors<<<1, 64, 0, stream>>>(cursors);
        bucket_points<<<nb, block, 0, stream>>>(
            positions, centroids, cursors, indices, npts);

        // Balanced chunked-XCD dispatch over the padded virtual-block space:
        // vtotal <= nb + KF; G = next multiple of 8; cpx = G/8.
        const int G = ((nb + KF + 7) / 8) * 8;
        const int cpx = G / 8;
        propnet_density_balanced<<<G, block, 0, stream>>>(
            positions, wsTab, W1, b1, W2, b2, cursors, indices, out, npts, cpx);
    } else if (ws_size >= need_h && d_ws != nullptr) {
        const int rthreads = NENT / 8;
        repack_tables_fp16<<<rthreads / 256, 256, 0, stream>>>(
            (const float4*)tables, (uint4*)d_ws, rthreads);
        propnet_density_kernel_h<<<nb, block, 0, stream>>>(
            positions, centroids, (const __half2*)d_ws, W1, b1, W2, b2, out, npts);
    } else {
        propnet_density_kernel_f<<<nb, block, 0, stream>>>(
            positions, centroids, tables, W1, b1, W2, b2, out, npts);
    }
}